// Round 1
// baseline (284.685 us; speedup 1.0000x reference)
//
#include <hip/hip_runtime.h>
#include <hip/hip_bf16.h>
#include <math.h>

typedef __bf16 bf16x8 __attribute__((ext_vector_type(8)));
typedef __bf16 bf16x4 __attribute__((ext_vector_type(4)));
typedef float  f32x4  __attribute__((ext_vector_type(4)));

#define D_DIM 512
#define P_DIM 128
#define MB    128
#define BK    64
#define LDA   72      // bf16 elements per LDS row (64 + 8 pad): row stride 144 B, 16B-aligned
#define TEMP  0.1f

// One block = 128 rows x all 128 prototypes. 256 threads = 4 waves.
// Wave w computes rows [w*32, w*32+32) x 128 cols via 2x8 tiles of 16x16x32 bf16 MFMA.
__global__ __launch_bounds__(256, 2)
void mrc_fused(const float* __restrict__ bfeat,
               const float* __restrict__ protos,
               const int*   __restrict__ labels,
               const float* __restrict__ weights,
               float*       __restrict__ out,
               int nrows)
{
    __shared__ __bf16 sA[MB * LDA];      // 18432 B
    __shared__ __bf16 sB[P_DIM * LDA];   // 18432 B
    __shared__ float  sScale[MB];
    __shared__ float  sRed[4];

    const int t    = threadIdx.x;
    const int lane = t & 63;
    const int wave = t >> 6;
    const int rgrp = t >> 4;     // 0..15 : row group for staging
    const int cidx = t & 15;     // float4 column within 64-wide K chunk
    const int q    = lane >> 4;  // quad 0..3
    const int cl   = lane & 15;

    const long long R0 = (long long)blockIdx.x * MB;

    // per-lane prototype weights for epilogue cols (col = ct*16 + cl)
    float wcol[8];
#pragma unroll
    for (int ct = 0; ct < 8; ++ct) wcol[ct] = weights[ct * 16 + cl];

    // per-thread sum-of-squares partials; thread handles rows i*16 + rgrp
    float ss[8];
#pragma unroll
    for (int i = 0; i < 8; ++i) ss[i] = 0.f;

    f32x4 acc[2][8];
#pragma unroll
    for (int mt = 0; mt < 2; ++mt)
#pragma unroll
        for (int ct = 0; ct < 8; ++ct) acc[mt][ct] = (f32x4){0.f, 0.f, 0.f, 0.f};

    for (int kc = 0; kc < D_DIM / BK; ++kc) {
        const int kbase = kc * BK;

        // ---- stage A tile (fp32 -> bf16) + accumulate row sum-of-squares ----
#pragma unroll
        for (int i = 0; i < 8; ++i) {
            const int row = i * 16 + rgrp;
            const float4 v = *(const float4*)(bfeat + (R0 + row) * D_DIM + kbase + cidx * 4);
            ss[i] += v.x * v.x + v.y * v.y + v.z * v.z + v.w * v.w;
            bf16x4 b;
            b[0] = (__bf16)v.x; b[1] = (__bf16)v.y; b[2] = (__bf16)v.z; b[3] = (__bf16)v.w;
            *(bf16x4*)&sA[row * LDA + cidx * 4] = b;
        }
        // ---- stage B tile (fp32 -> bf16); protos are 256 KB, L2-resident ----
#pragma unroll
        for (int i = 0; i < 8; ++i) {
            const int row = i * 16 + rgrp;
            const float4 v = *(const float4*)(protos + row * D_DIM + kbase + cidx * 4);
            bf16x4 b;
            b[0] = (__bf16)v.x; b[1] = (__bf16)v.y; b[2] = (__bf16)v.z; b[3] = (__bf16)v.w;
            *(bf16x4*)&sB[row * LDA + cidx * 4] = b;
        }
        __syncthreads();

        // ---- MFMA: 2 k-steps of K=32 ----
#pragma unroll
        for (int ks = 0; ks < 2; ++ks) {
            const int k0 = ks * 32;
            bf16x8 af[2];
#pragma unroll
            for (int mt = 0; mt < 2; ++mt) {
                const int r = wave * 32 + mt * 16 + cl;   // A[m = lane&15][k = q*8 + j]
                af[mt] = *(const bf16x8*)&sA[r * LDA + k0 + q * 8];
            }
#pragma unroll
            for (int ct = 0; ct < 8; ++ct) {
                const int n = ct * 16 + cl;               // B[n = lane&15][k = q*8 + j]
                const bf16x8 bfr = *(const bf16x8*)&sB[n * LDA + k0 + q * 8];
#pragma unroll
                for (int mt = 0; mt < 2; ++mt)
                    acc[mt][ct] = __builtin_amdgcn_mfma_f32_16x16x32_bf16(af[mt], bfr, acc[mt][ct], 0, 0, 0);
            }
        }
        __syncthreads();
    }

    // ---- per-row norm -> logit scale = 1 / (max(||x||, eps) * T) ----
#pragma unroll
    for (int i = 0; i < 8; ++i) {
        float s = ss[i];
        s += __shfl_xor(s, 1, 16);
        s += __shfl_xor(s, 2, 16);
        s += __shfl_xor(s, 4, 16);
        s += __shfl_xor(s, 8, 16);
        if (cl == 0) {
            const int row = i * 16 + rgrp;
            const float nrm = fmaxf(sqrtf(s), 1e-12f);
            sScale[row] = 1.0f / (nrm * TEMP);
        }
    }
    __syncthreads();

    // ---- epilogue: per-row masked log-softmax reduction ----
    // C/D layout: col = lane&15 (+16*ct), row = q*4 + reg (+16*mt, +32*wave)
    float pos_acc = 0.f;
#pragma unroll
    for (int mt = 0; mt < 2; ++mt) {
#pragma unroll
        for (int reg = 0; reg < 4; ++reg) {
            const int rl = wave * 32 + mt * 16 + q * 4 + reg;
            const float scale = sScale[rl];
            float lg[8];
            float m = -3.4e38f;
#pragma unroll
            for (int ct = 0; ct < 8; ++ct) {
                lg[ct] = acc[mt][ct][reg] * scale;
                m = fmaxf(m, lg[ct]);
            }
            m = fmaxf(m, __shfl_xor(m, 1, 16));
            m = fmaxf(m, __shfl_xor(m, 2, 16));
            m = fmaxf(m, __shfl_xor(m, 4, 16));
            m = fmaxf(m, __shfl_xor(m, 8, 16));

            const int* lrow = labels + (R0 + rl) * (long long)P_DIM;
            float s = 0.f, p = 0.f, msum = 0.f;
#pragma unroll
            for (int ct = 0; ct < 8; ++ct) {
                const float mask = (float)lrow[ct * 16 + cl] * wcol[ct];
                const float z = lg[ct] - m;
                s    += __expf(z) * (1.0f - mask);
                p    += mask * z;
                msum += mask;
            }
            s += __shfl_xor(s, 1, 16);
            s += __shfl_xor(s, 2, 16);
            s += __shfl_xor(s, 4, 16);
            s += __shfl_xor(s, 8, 16);
            // sum(mask * (z - log S)) = sum(mask*z) - log(S)*sum(mask)
            pos_acc += p - logf(s) * msum;
        }
    }

    // ---- block reduction -> one atomicAdd ----
    pos_acc += __shfl_xor(pos_acc, 1);
    pos_acc += __shfl_xor(pos_acc, 2);
    pos_acc += __shfl_xor(pos_acc, 4);
    pos_acc += __shfl_xor(pos_acc, 8);
    pos_acc += __shfl_xor(pos_acc, 16);
    pos_acc += __shfl_xor(pos_acc, 32);
    if (lane == 0) sRed[wave] = pos_acc;
    __syncthreads();
    if (t == 0) {
        const float total = sRed[0] + sRed[1] + sRed[2] + sRed[3];
        // loss = LAMBDA * (-(T/BT) * sum(mean_log_prob_pos)) / n ; LAMBDA=1, BT=1
        atomicAdd(out, total * (-TEMP / (float)nrows));
    }
}

extern "C" void kernel_launch(void* const* d_in, const int* in_sizes, int n_in,
                              void* d_out, int out_size, void* d_ws, size_t ws_size,
                              hipStream_t stream) {
    const float* bfeat   = (const float*)d_in[2];
    const float* protos  = (const float*)d_in[3];
    const int*   labels  = (const int*)d_in[4];
    const float* weights = (const float*)d_in[5];
    float* out = (float*)d_out;

    const int nrows = in_sizes[2] / D_DIM;   // 65536

    hipMemsetAsync(d_out, 0, sizeof(float) * out_size, stream);
    const int nblocks = nrows / MB;          // 512
    mrc_fused<<<nblocks, 256, 0, stream>>>(bfeat, protos, labels, weights, out, nrows);
}

// Round 2
// 257.549 us; speedup vs baseline: 1.1054x; 1.1054x over previous
//
#include <hip/hip_runtime.h>
#include <hip/hip_bf16.h>
#include <math.h>

typedef __bf16 bf16x8v __attribute__((ext_vector_type(8)));
typedef __bf16 bf16x4v __attribute__((ext_vector_type(4)));
typedef float  f32x4   __attribute__((ext_vector_type(4)));

#define D_DIM 512
#define P_DIM 128
#define LDB   520            // bf16 per LDS B row: 512 + 8 pad -> 260 dwords stride.
                             // 260 % 32 == 4, so consecutive 8-lane groups of a
                             // ds_read_b128 cover all 32 banks -> conflict-free.
#define TEMP  0.1f
#define ROWS_PER_BLOCK 256
#define THREADS 1024

// 256 blocks (1/CU, LDS-limited) x 16 waves. B (prototypes) persistent in LDS.
// Each wave owns 16 rows x all 128 prototypes; NO barriers in the main loop.
__global__ __launch_bounds__(THREADS, 4)
void mrc_fused(const float* __restrict__ bfeat,
               const float* __restrict__ protos,
               const int*   __restrict__ labels,
               const float* __restrict__ weights,
               float*       __restrict__ out,
               int nrows)
{
    __shared__ __bf16 sB[P_DIM * LDB];   // 133120 B
    __shared__ float  sRed[16];

    const int t    = threadIdx.x;
    const int lane = t & 63;
    const int wave = t >> 6;
    const int q    = lane >> 4;   // quad 0..3
    const int cl   = lane & 15;

    // ---- stage prototypes fp32 -> bf16 into LDS, once per block ----
#pragma unroll
    for (int i = 0; i < 16; ++i) {
        const int f   = i * THREADS + t;     // 0..16383 float4s
        const int row = f >> 7;              // /128
        const int c4  = f & 127;
        const float4 v = *(const float4*)(protos + row * D_DIM + c4 * 4);
        bf16x4v b;
        b[0] = (__bf16)v.x; b[1] = (__bf16)v.y; b[2] = (__bf16)v.z; b[3] = (__bf16)v.w;
        *(bf16x4v*)&sB[row * LDB + c4 * 4] = b;
    }
    __syncthreads();   // the only block-wide barrier before the final reduction

    // ---- each wave: 16 rows, direct global->register A fragments ----
    // A-operand layout for mfma_f32_16x16x32_bf16: A[m = lane&15][k = q*8 + j]
    const long long r0 = (long long)blockIdx.x * ROWS_PER_BLOCK + wave * 16;
    const float* arow = bfeat + (r0 + cl) * (long long)D_DIM + q * 8;

    float wcol[8];
#pragma unroll
    for (int ct = 0; ct < 8; ++ct) wcol[ct] = weights[ct * 16 + cl];

    f32x4 acc[8];
#pragma unroll
    for (int ct = 0; ct < 8; ++ct) acc[ct] = (f32x4){0.f, 0.f, 0.f, 0.f};

    float ss = 0.f;
    float4 p0 = *(const float4*)(arow);
    float4 p1 = *(const float4*)(arow + 4);

#pragma unroll 4
    for (int ks = 0; ks < 16; ++ks) {
        const float4 c0 = p0, c1 = p1;
        if (ks < 15) {
            p0 = *(const float4*)(arow + (ks + 1) * 32);
            p1 = *(const float4*)(arow + (ks + 1) * 32 + 4);
        }
        ss += c0.x*c0.x + c0.y*c0.y + c0.z*c0.z + c0.w*c0.w
            + c1.x*c1.x + c1.y*c1.y + c1.z*c1.z + c1.w*c1.w;
        bf16x8v af;
        af[0]=(__bf16)c0.x; af[1]=(__bf16)c0.y; af[2]=(__bf16)c0.z; af[3]=(__bf16)c0.w;
        af[4]=(__bf16)c1.x; af[5]=(__bf16)c1.y; af[6]=(__bf16)c1.z; af[7]=(__bf16)c1.w;
        const int k0 = ks * 32 + q * 8;
#pragma unroll
        for (int ct = 0; ct < 8; ++ct) {
            const bf16x8v bfr = *(const bf16x8v*)&sB[(ct * 16 + cl) * LDB + k0];
            acc[ct] = __builtin_amdgcn_mfma_f32_16x16x32_bf16(af, bfr, acc[ct], 0, 0, 0);
        }
    }

    // ---- row norms: lane(cl,q) holds 128 of row cl's 512 squares ----
    ss += __shfl_xor(ss, 16);
    ss += __shfl_xor(ss, 32);
    const float scale = 1.0f / (fmaxf(sqrtf(ss), 1e-12f) * TEMP);  // for row cl

    // ---- epilogue: masked log-softmax per row ----
    // C/D layout: col = ct*16 + (lane&15), row = q*4 + reg
    float pos_acc = 0.f;
#pragma unroll
    for (int reg = 0; reg < 4; ++reg) {
        const int rl = q * 4 + reg;                      // row within wave tile
        const float rscale = __shfl(scale, rl, 16);      // scale lives in lane cl==rl
        float lg[8];
        float m = -3.4e38f;
#pragma unroll
        for (int ct = 0; ct < 8; ++ct) {
            lg[ct] = acc[ct][reg] * rscale;
            m = fmaxf(m, lg[ct]);
        }
        m = fmaxf(m, __shfl_xor(m, 1, 16));
        m = fmaxf(m, __shfl_xor(m, 2, 16));
        m = fmaxf(m, __shfl_xor(m, 4, 16));
        m = fmaxf(m, __shfl_xor(m, 8, 16));

        const int* lrow = labels + (r0 + rl) * (long long)P_DIM;
        float s = 0.f, p = 0.f, msum = 0.f;
#pragma unroll
        for (int ct = 0; ct < 8; ++ct) {
            const float mask = (float)lrow[ct * 16 + cl] * wcol[ct];
            const float z = lg[ct] - m;
            s    += __expf(z) * (1.0f - mask);
            p    += mask * z;
            msum += mask;
        }
        s += __shfl_xor(s, 1, 16);
        s += __shfl_xor(s, 2, 16);
        s += __shfl_xor(s, 4, 16);
        s += __shfl_xor(s, 8, 16);
        // sum(mask*(z - log S)) = sum(mask*z) - log(S)*sum(mask)
        pos_acc += p - logf(s) * msum;
    }

    // ---- block reduction -> one atomicAdd ----
    pos_acc += __shfl_xor(pos_acc, 1);
    pos_acc += __shfl_xor(pos_acc, 2);
    pos_acc += __shfl_xor(pos_acc, 4);
    pos_acc += __shfl_xor(pos_acc, 8);
    pos_acc += __shfl_xor(pos_acc, 16);
    pos_acc += __shfl_xor(pos_acc, 32);
    if (lane == 0) sRed[wave] = pos_acc;
    __syncthreads();
    if (t == 0) {
        float total = 0.f;
#pragma unroll
        for (int w = 0; w < 16; ++w) total += sRed[w];
        // loss = LAMBDA * (-(T/BT) * sum(mean_log_prob_pos)) / n ; LAMBDA=1, BT=1
        atomicAdd(out, total * (-TEMP / (float)nrows));
    }
}

extern "C" void kernel_launch(void* const* d_in, const int* in_sizes, int n_in,
                              void* d_out, int out_size, void* d_ws, size_t ws_size,
                              hipStream_t stream) {
    const float* bfeat   = (const float*)d_in[2];
    const float* protos  = (const float*)d_in[3];
    const int*   labels  = (const int*)d_in[4];
    const float* weights = (const float*)d_in[5];
    float* out = (float*)d_out;

    const int nrows = in_sizes[2] / D_DIM;         // 65536

    hipMemsetAsync(d_out, 0, sizeof(float) * out_size, stream);
    const int nblocks = nrows / ROWS_PER_BLOCK;    // 256
    mrc_fused<<<nblocks, THREADS, 0, stream>>>(bfeat, protos, labels, weights, out, nrows);
}

// Round 3
// 255.581 us; speedup vs baseline: 1.1139x; 1.0077x over previous
//
#include <hip/hip_runtime.h>
#include <hip/hip_bf16.h>
#include <math.h>

typedef __bf16 bf16x8v __attribute__((ext_vector_type(8)));
typedef __bf16 bf16x4v __attribute__((ext_vector_type(4)));
typedef float  f32x4   __attribute__((ext_vector_type(4)));

#define D_DIM 512
#define P_DIM 128
#define LDB   520            // bf16 per LDS B row: 512 + 8 pad -> 260 dwords stride.
                             // 260 % 32 == 4 -> ds_read_b128 conflict-free.
#define TEMP  0.1f
#define ROWS_PER_BLOCK 256
#define THREADS 1024

// 256 blocks (1/CU, LDS-limited) x 16 waves. B (prototypes) persistent in LDS.
// Each wave owns 16 rows x all 128 prototypes; NO barriers in the main loop.
// R3: distance-2 A prefetch, label prefetch into VGPRs, NT loads for streams.
__global__ __launch_bounds__(THREADS, 4)
void mrc_fused(const float* __restrict__ bfeat,
               const float* __restrict__ protos,
               const int*   __restrict__ labels,
               const float* __restrict__ weights,
               float*       __restrict__ out,
               int nrows)
{
    __shared__ __bf16 sB[P_DIM * LDB];   // 133120 B
    __shared__ float  sRed[16];

    const int t    = threadIdx.x;
    const int lane = t & 63;
    const int wave = t >> 6;
    const int q    = lane >> 4;   // quad 0..3
    const int cl   = lane & 15;

    const long long r0 = (long long)blockIdx.x * ROWS_PER_BLOCK + wave * 16;

    // ---- label prefetch: issue the 32 scattered dword loads NOW so they
    // complete under the GEMM stream; consumed from registers in the epilogue.
    // lane(cl,q) needs labels[row = q*4+reg][col = ct*16+cl]
    int lab[4][8];
    {
        const int* lbase = labels + r0 * (long long)P_DIM;
#pragma unroll
        for (int reg = 0; reg < 4; ++reg)
#pragma unroll
            for (int ct = 0; ct < 8; ++ct)
                lab[reg][ct] = __builtin_nontemporal_load(
                    lbase + (q * 4 + reg) * P_DIM + ct * 16 + cl);
    }

    // ---- stage prototypes fp32 -> bf16 into LDS, once per block ----
#pragma unroll
    for (int i = 0; i < 16; ++i) {
        const int f   = i * THREADS + t;     // 0..16383 float4s
        const int row = f >> 7;              // /128
        const int c4  = f & 127;
        const f32x4 v = *(const f32x4*)(protos + row * D_DIM + c4 * 4);
        bf16x4v b;
        b[0] = (__bf16)v[0]; b[1] = (__bf16)v[1]; b[2] = (__bf16)v[2]; b[3] = (__bf16)v[3];
        *(bf16x4v*)&sB[row * LDB + c4 * 4] = b;
    }
    __syncthreads();   // the only block-wide barrier before the final reduction

    // ---- each wave: 16 rows, direct global->register A fragments ----
    // A-operand layout for mfma_f32_16x16x32_bf16: A[m = lane&15][k = q*8 + j]
    const float* arow = bfeat + (r0 + cl) * (long long)D_DIM + q * 8;

    float wcol[8];
#pragma unroll
    for (int ct = 0; ct < 8; ++ct) wcol[ct] = weights[ct * 16 + cl];

    f32x4 acc[8];
#pragma unroll
    for (int ct = 0; ct < 8; ++ct) acc[ct] = (f32x4){0.f, 0.f, 0.f, 0.f};

    float ss = 0.f;
    // distance-2 prefetch: 4 float4 in flight per wave
    f32x4 p[2][2];
    p[0][0] = __builtin_nontemporal_load((const f32x4*)(arow));
    p[0][1] = __builtin_nontemporal_load((const f32x4*)(arow + 4));
    p[1][0] = __builtin_nontemporal_load((const f32x4*)(arow + 32));
    p[1][1] = __builtin_nontemporal_load((const f32x4*)(arow + 36));

#pragma unroll 4
    for (int ks = 0; ks < 16; ++ks) {
        const f32x4 c0 = p[ks & 1][0], c1 = p[ks & 1][1];
        if (ks < 14) {
            p[ks & 1][0] = __builtin_nontemporal_load((const f32x4*)(arow + (ks + 2) * 32));
            p[ks & 1][1] = __builtin_nontemporal_load((const f32x4*)(arow + (ks + 2) * 32 + 4));
        }
        ss += c0[0]*c0[0] + c0[1]*c0[1] + c0[2]*c0[2] + c0[3]*c0[3]
            + c1[0]*c1[0] + c1[1]*c1[1] + c1[2]*c1[2] + c1[3]*c1[3];
        bf16x8v af;
        af[0]=(__bf16)c0[0]; af[1]=(__bf16)c0[1]; af[2]=(__bf16)c0[2]; af[3]=(__bf16)c0[3];
        af[4]=(__bf16)c1[0]; af[5]=(__bf16)c1[1]; af[6]=(__bf16)c1[2]; af[7]=(__bf16)c1[3];
        const int k0 = ks * 32 + q * 8;
#pragma unroll
        for (int ct = 0; ct < 8; ++ct) {
            const bf16x8v bfr = *(const bf16x8v*)&sB[(ct * 16 + cl) * LDB + k0];
            acc[ct] = __builtin_amdgcn_mfma_f32_16x16x32_bf16(af, bfr, acc[ct], 0, 0, 0);
        }
    }

    // ---- row norms: lane(cl,q) holds 128 of row cl's 512 squares ----
    ss += __shfl_xor(ss, 16);
    ss += __shfl_xor(ss, 32);
    const float scale = 1.0f / (fmaxf(sqrtf(ss), 1e-12f) * TEMP);  // for row cl

    // ---- epilogue: masked log-softmax per row ----
    // C/D layout: col = ct*16 + (lane&15), row = q*4 + reg
    float pos_acc = 0.f;
#pragma unroll
    for (int reg = 0; reg < 4; ++reg) {
        const float rscale = __shfl(scale, q * 4 + reg, 16);  // scale lives in lane cl==row
        float lg[8];
        float m = -3.4e38f;
#pragma unroll
        for (int ct = 0; ct < 8; ++ct) {
            lg[ct] = acc[ct][reg] * rscale;
            m = fmaxf(m, lg[ct]);
        }
        m = fmaxf(m, __shfl_xor(m, 1, 16));
        m = fmaxf(m, __shfl_xor(m, 2, 16));
        m = fmaxf(m, __shfl_xor(m, 4, 16));
        m = fmaxf(m, __shfl_xor(m, 8, 16));

        float s = 0.f, pz = 0.f, msum = 0.f;
#pragma unroll
        for (int ct = 0; ct < 8; ++ct) {
            const float mask = (float)lab[reg][ct] * wcol[ct];
            const float z = lg[ct] - m;
            s    += __expf(z) * (1.0f - mask);
            pz   += mask * z;
            msum += mask;
        }
        s += __shfl_xor(s, 1, 16);
        s += __shfl_xor(s, 2, 16);
        s += __shfl_xor(s, 4, 16);
        s += __shfl_xor(s, 8, 16);
        // sum(mask*(z - log S)) = sum(mask*z) - log(S)*sum(mask)
        pos_acc += pz - logf(s) * msum;
    }

    // ---- block reduction -> one atomicAdd ----
    pos_acc += __shfl_xor(pos_acc, 1);
    pos_acc += __shfl_xor(pos_acc, 2);
    pos_acc += __shfl_xor(pos_acc, 4);
    pos_acc += __shfl_xor(pos_acc, 8);
    pos_acc += __shfl_xor(pos_acc, 16);
    pos_acc += __shfl_xor(pos_acc, 32);
    if (lane == 0) sRed[wave] = pos_acc;
    __syncthreads();
    if (t == 0) {
        float total = 0.f;
#pragma unroll
        for (int w = 0; w < 16; ++w) total += sRed[w];
        // loss = LAMBDA * (-(T/BT) * sum(mean_log_prob_pos)) / n ; LAMBDA=1, BT=1
        atomicAdd(out, total * (-TEMP / (float)nrows));
    }
}

extern "C" void kernel_launch(void* const* d_in, const int* in_sizes, int n_in,
                              void* d_out, int out_size, void* d_ws, size_t ws_size,
                              hipStream_t stream) {
    const float* bfeat   = (const float*)d_in[2];
    const float* protos  = (const float*)d_in[3];
    const int*   labels  = (const int*)d_in[4];
    const float* weights = (const float*)d_in[5];
    float* out = (float*)d_out;

    const int nrows = in_sizes[2] / D_DIM;         // 65536

    hipMemsetAsync(d_out, 0, sizeof(float) * out_size, stream);
    const int nblocks = nrows / ROWS_PER_BLOCK;    // 256
    mrc_fused<<<nblocks, THREADS, 0, stream>>>(bfeat, protos, labels, weights, out, nrows);
}